// Round 3
// baseline (139.541 us; speedup 1.0000x reference)
//
#include <hip/hip_runtime.h>

// DeformableDETR loss, single fused kernel. B=1024, Q=900, C=8, Nt=32.
// R2: one 512-thread block per image (4 blocks/CU x 8 waves = 32 waves/CU);
//     per-image losses pre-weighted and atomicAdd'ed straight into d_out
//     (zeroed via hipMemsetAsync — capture-safe). Finalize kernel deleted.
// Class lookup: LDS table built with atomicMax on (t<<8|label); max over t
// reproduces numpy's last-wins scatter exactly.

constexpr int Bc  = 1024;
constexpr int Qc  = 900;
constexpr int Cc  = 8;
constexpr int NTc = 32;
constexpr float kAlpha = 0.25f;

__device__ inline float wave_reduce(float v) {
#pragma unroll
    for (int o = 32; o > 0; o >>= 1) v += __shfl_down(v, o, 64);
    return v;
}

__global__ __launch_bounds__(512) void detr_main(
    const float* __restrict__ logits,   // [B,Q,C]
    const float* __restrict__ pboxes,   // [B,Q,4] cxcywh
    const float* __restrict__ tboxes,   // [B,Nt,4] cxcywh
    const int*   __restrict__ sidx,     // [B,Nt]
    const int*   __restrict__ tlbl,     // [B,Nt]
    const float* __restrict__ ew,       // [C+1]
    float*       __restrict__ out)      // [4], pre-zeroed
{
    const int b   = blockIdx.x;
    const int tid = threadIdx.x;

    __shared__ int   s_cls[Qc];        // packed (t<<8)|label, -1 = background
    __shared__ int   s_src[NTc];
    __shared__ int   s_lbl[NTc];
    __shared__ float s_ew[Cc + 1];
    __shared__ float s_red[8][4];

    for (int i = tid; i < Qc; i += 512) s_cls[i] = -1;
    if (tid < NTc) {
        s_src[tid] = sidx[b * NTc + tid];
        s_lbl[tid] = tlbl[b * NTc + tid];
    }
    if (tid < Cc + 1) s_ew[tid] = ew[tid];
    __syncthreads();
    if (tid < NTc) atomicMax(&s_cls[s_src[tid]], (tid << 8) | s_lbl[tid]);
    __syncthreads();

    // ---- focal CE + cardinality over this image's queries ----
    float ce = 0.f, card = 0.f;
    for (int q = tid; q < Qc; q += 512) {
        const int packed = s_cls[q];
        const int tgt = (packed < 0) ? Cc : (packed & 0xFF);

        const float4* lp = (const float4*)(logits + ((size_t)(b * Qc + q)) * Cc);
        float4 xa = lp[0], xb = lp[1];
        float xs[8] = {xa.x, xa.y, xa.z, xa.w, xb.x, xb.y, xb.z, xb.w};

        float fs = 0.f, mx = -1e30f;
#pragma unroll
        for (int c = 0; c < Cc; ++c) {
            float x   = xs[c];
            mx        = fmaxf(mx, x);
            bool  oh  = (c == tgt);
            float e   = __expf(-fabsf(x));
            float l1p = __logf(1.f + e);                 // log1p(exp(-|x|))
            float bce = fmaxf(x, 0.f) - (oh ? x : 0.f) + l1p;
            float inv = 1.f / (1.f + e);                 // sigmoid(|x|)
            float p   = (x >= 0.f) ? inv : (1.f - inv);  // sigmoid(x)
            float pt  = oh ? p : (1.f - p);
            float om  = 1.f - pt;
            fs += (oh ? kAlpha : (1.f - kAlpha)) * om * om * bce;
        }
        ce   += fs * s_ew[tgt];
        card += (mx > 0.f) ? 1.f : 0.f;   // sigmoid(max)>0.5 <=> max logit>0
    }

    // ---- matched-box L1 + GIoU (threads 0..31, one per target) ----
    float lbb = 0.f, lgi = 0.f;
    if (tid < NTc) {
        int q = s_src[tid], lab = s_lbl[tid];
        float4 sb = *(const float4*)(pboxes + ((size_t)(b * Qc + q)) * 4);
        float4 tb = *(const float4*)(tboxes + ((size_t)(b * NTc + tid)) * 4);
        float scale = (lab == 4 || lab == 5 || lab == 6) ? 2.f : 1.f;

        lbb = (fabsf(sb.x - tb.x) + fabsf(sb.y - tb.y) +
               fabsf(sb.z - tb.z) + fabsf(sb.w - tb.w)) * scale;

        float ax0 = sb.x - 0.5f * sb.z, ay0 = sb.y - 0.5f * sb.w;
        float ax1 = sb.x + 0.5f * sb.z, ay1 = sb.y + 0.5f * sb.w;
        float bx0 = tb.x - 0.5f * tb.z, by0 = tb.y - 0.5f * tb.w;
        float bx1 = tb.x + 0.5f * tb.z, by1 = tb.y + 0.5f * tb.w;

        float areaA = (ax1 - ax0) * (ay1 - ay0);
        float areaB = (bx1 - bx0) * (by1 - by0);
        float iw = fmaxf(fminf(ax1, bx1) - fmaxf(ax0, bx0), 0.f);
        float ih = fmaxf(fminf(ay1, by1) - fmaxf(ay0, by0), 0.f);
        float inter = iw * ih;
        float uni   = areaA + areaB - inter;
        float iou   = inter / uni;
        float ewd = fmaxf(fmaxf(ax1, bx1) - fminf(ax0, bx0), 0.f);
        float ehd = fmaxf(fmaxf(ay1, by1) - fminf(ay0, by0), 0.f);
        float areaE = ewd * ehd;
        float g = iou - (areaE - uni) / areaE;
        lgi = (1.f - g) * scale;
    }

    // ---- block reduce {ce, lbb, lgi, card} across 8 waves ----
    float vals[4] = {ce, lbb, lgi, card};
    const int lane = tid & 63, wave = tid >> 6;
#pragma unroll
    for (int k = 0; k < 4; ++k) {
        float v = wave_reduce(vals[k]);
        if (lane == 0) s_red[wave][k] = v;
    }
    __syncthreads();
    if (tid == 0) {
        float s[4];
#pragma unroll
        for (int k = 0; k < 4; ++k) {
            float a = 0.f;
#pragma unroll
            for (int w = 0; w < 8; ++w) a += s_red[w][k];
            s[k] = a;
        }
        const float nb = (float)(Bc * NTc) + 1e-8f;   // num_boxes
        atomicAdd(&out[0], 1.0f * s[0] / nb);                     // W_CE
        atomicAdd(&out[1], 5.0f * s[1] / nb);                     // W_BBOX
        atomicAdd(&out[2], 2.0f * s[2] / nb);                     // W_GIOU
        atomicAdd(&out[3], fabsf(s[3] - (float)NTc) / (float)Bc); // W_CARD
    }
}

extern "C" void kernel_launch(void* const* d_in, const int* in_sizes, int n_in,
                              void* d_out, int out_size, void* d_ws, size_t ws_size,
                              hipStream_t stream) {
    const float* logits = (const float*)d_in[0];
    const float* pboxes = (const float*)d_in[1];
    const float* tboxes = (const float*)d_in[2];
    const int*   sidx   = (const int*)d_in[3];
    const int*   tlbl   = (const int*)d_in[4];
    const float* ew     = (const float*)d_in[5];
    float* out = (float*)d_out;

    hipMemsetAsync(out, 0, (size_t)out_size * sizeof(float), stream);
    detr_main<<<Bc, 512, 0, stream>>>(logits, pboxes, tboxes, sidx, tlbl, ew, out);
}

// Round 4
// 95.134 us; speedup vs baseline: 1.4668x; 1.4668x over previous
//
#include <hip/hip_runtime.h>

// DeformableDETR loss. B=1024, Q=900, C=8, Nt=32.
// R3: R2's fused per-image kernel (1024 blocks x 512 thr, block-local
//     cardinality) but per-image float4 partials to ws via PLAIN STORES —
//     R2's 4096 same-line device atomicAdds serialized at ~13 ns each and
//     cost +52 us (detr_main 66 us, VALUBusy 13.7%). Finalize kernel reduces
//     1024 partials and writes d_out directly (no memset needed).
// Class lookup: LDS table via atomicMax on (t<<8|label); max over t ==
// numpy last-wins scatter.

constexpr int Bc  = 1024;
constexpr int Qc  = 900;
constexpr int Cc  = 8;
constexpr int NTc = 32;
constexpr float kAlpha = 0.25f;

__device__ inline float wave_reduce(float v) {
#pragma unroll
    for (int o = 32; o > 0; o >>= 1) v += __shfl_down(v, o, 64);
    return v;
}

__global__ __launch_bounds__(512) void detr_partial(
    const float* __restrict__ logits,   // [B,Q,C]
    const float* __restrict__ pboxes,   // [B,Q,4] cxcywh
    const float* __restrict__ tboxes,   // [B,Nt,4] cxcywh
    const int*   __restrict__ sidx,     // [B,Nt]
    const int*   __restrict__ tlbl,     // [B,Nt]
    const float* __restrict__ ew,       // [C+1]
    float4*      __restrict__ partials) // [B] {ce, bbox, giou, |card-Nt|}
{
    const int b   = blockIdx.x;
    const int tid = threadIdx.x;

    __shared__ int   s_cls[Qc];        // packed (t<<8)|label, -1 = background
    __shared__ int   s_src[NTc];
    __shared__ int   s_lbl[NTc];
    __shared__ float s_ew[Cc + 1];
    __shared__ float s_red[8][4];

    for (int i = tid; i < Qc; i += 512) s_cls[i] = -1;
    if (tid < NTc) {
        s_src[tid] = sidx[b * NTc + tid];
        s_lbl[tid] = tlbl[b * NTc + tid];
    }
    if (tid < Cc + 1) s_ew[tid] = ew[tid];
    __syncthreads();
    if (tid < NTc) atomicMax(&s_cls[s_src[tid]], (tid << 8) | s_lbl[tid]);
    __syncthreads();

    // ---- focal CE + cardinality over this image's queries ----
    float ce = 0.f, card = 0.f;
    for (int q = tid; q < Qc; q += 512) {
        const int packed = s_cls[q];
        const int tgt = (packed < 0) ? Cc : (packed & 0xFF);

        const float4* lp = (const float4*)(logits + ((size_t)(b * Qc + q)) * Cc);
        float4 xa = lp[0], xb = lp[1];
        float xs[8] = {xa.x, xa.y, xa.z, xa.w, xb.x, xb.y, xb.z, xb.w};

        float fs = 0.f, mx = -1e30f;
#pragma unroll
        for (int c = 0; c < Cc; ++c) {
            float x   = xs[c];
            mx        = fmaxf(mx, x);
            bool  oh  = (c == tgt);
            float e   = __expf(-fabsf(x));
            float l1p = __logf(1.f + e);                 // log1p(exp(-|x|))
            float bce = fmaxf(x, 0.f) - (oh ? x : 0.f) + l1p;
            float inv = 1.f / (1.f + e);                 // sigmoid(|x|)
            float p   = (x >= 0.f) ? inv : (1.f - inv);  // sigmoid(x)
            float pt  = oh ? p : (1.f - p);
            float om  = 1.f - pt;
            fs += (oh ? kAlpha : (1.f - kAlpha)) * om * om * bce;
        }
        ce   += fs * s_ew[tgt];
        card += (mx > 0.f) ? 1.f : 0.f;   // sigmoid(max)>0.5 <=> max logit>0
    }

    // ---- matched-box L1 + GIoU (threads 0..31, one per target) ----
    float lbb = 0.f, lgi = 0.f;
    if (tid < NTc) {
        int q = s_src[tid], lab = s_lbl[tid];
        float4 sb = *(const float4*)(pboxes + ((size_t)(b * Qc + q)) * 4);
        float4 tb = *(const float4*)(tboxes + ((size_t)(b * NTc + tid)) * 4);
        float scale = (lab == 4 || lab == 5 || lab == 6) ? 2.f : 1.f;

        lbb = (fabsf(sb.x - tb.x) + fabsf(sb.y - tb.y) +
               fabsf(sb.z - tb.z) + fabsf(sb.w - tb.w)) * scale;

        float ax0 = sb.x - 0.5f * sb.z, ay0 = sb.y - 0.5f * sb.w;
        float ax1 = sb.x + 0.5f * sb.z, ay1 = sb.y + 0.5f * sb.w;
        float bx0 = tb.x - 0.5f * tb.z, by0 = tb.y - 0.5f * tb.w;
        float bx1 = tb.x + 0.5f * tb.z, by1 = tb.y + 0.5f * tb.w;

        float areaA = (ax1 - ax0) * (ay1 - ay0);
        float areaB = (bx1 - bx0) * (by1 - by0);
        float iw = fmaxf(fminf(ax1, bx1) - fmaxf(ax0, bx0), 0.f);
        float ih = fmaxf(fminf(ay1, by1) - fmaxf(ay0, by0), 0.f);
        float inter = iw * ih;
        float uni   = areaA + areaB - inter;
        float iou   = inter / uni;
        float ewd = fmaxf(fmaxf(ax1, bx1) - fminf(ax0, bx0), 0.f);
        float ehd = fmaxf(fmaxf(ay1, by1) - fminf(ay0, by0), 0.f);
        float areaE = ewd * ehd;
        float g = iou - (areaE - uni) / areaE;
        lgi = (1.f - g) * scale;
    }

    // ---- block reduce {ce, lbb, lgi, card} across 8 waves ----
    float vals[4] = {ce, lbb, lgi, card};
    const int lane = tid & 63, wave = tid >> 6;
#pragma unroll
    for (int k = 0; k < 4; ++k) {
        float v = wave_reduce(vals[k]);
        if (lane == 0) s_red[wave][k] = v;
    }
    __syncthreads();
    if (tid == 0) {
        float s[4];
#pragma unroll
        for (int k = 0; k < 4; ++k) {
            float a = 0.f;
#pragma unroll
            for (int w = 0; w < 8; ++w) a += s_red[w][k];
            s[k] = a;
        }
        float4 r;
        r.x = s[0];
        r.y = s[1];
        r.z = s[2];
        r.w = fabsf(s[3] - (float)NTc);   // per-image |card - Nt|
        partials[b] = r;
    }
}

__global__ __launch_bounds__(256) void detr_finalize(
    const float4* __restrict__ partials, float* __restrict__ out)
{
    const int tid = threadIdx.x;
    __shared__ float s_red[4][4];

    float4 a = {0.f, 0.f, 0.f, 0.f};
    for (int i = tid; i < Bc; i += 256) {
        float4 p = partials[i];
        a.x += p.x; a.y += p.y; a.z += p.z; a.w += p.w;
    }
    float vals[4] = {a.x, a.y, a.z, a.w};
    const int lane = tid & 63, wave = tid >> 6;
#pragma unroll
    for (int k = 0; k < 4; ++k) {
        float v = wave_reduce(vals[k]);
        if (lane == 0) s_red[wave][k] = v;
    }
    __syncthreads();
    if (tid == 0) {
        float ce   = s_red[0][0] + s_red[1][0] + s_red[2][0] + s_red[3][0];
        float bbox = s_red[0][1] + s_red[1][1] + s_red[2][1] + s_red[3][1];
        float giou = s_red[0][2] + s_red[1][2] + s_red[2][2] + s_red[3][2];
        float card = s_red[0][3] + s_red[1][3] + s_red[2][3] + s_red[3][3];
        const float nb = (float)(Bc * NTc) + 1e-8f;   // num_boxes
        out[0] = 1.0f * ce   / nb;          // W_CE
        out[1] = 5.0f * bbox / nb;          // W_BBOX
        out[2] = 2.0f * giou / nb;          // W_GIOU
        out[3] = 1.0f * card / (float)Bc;   // W_CARD, mean over images
    }
}

extern "C" void kernel_launch(void* const* d_in, const int* in_sizes, int n_in,
                              void* d_out, int out_size, void* d_ws, size_t ws_size,
                              hipStream_t stream) {
    const float* logits = (const float*)d_in[0];
    const float* pboxes = (const float*)d_in[1];
    const float* tboxes = (const float*)d_in[2];
    const int*   sidx   = (const int*)d_in[3];
    const int*   tlbl   = (const int*)d_in[4];
    const float* ew     = (const float*)d_in[5];
    float4* partials = (float4*)d_ws;   // 1024 * 16 B = 16 KiB

    detr_partial<<<Bc, 512, 0, stream>>>(logits, pboxes, tboxes, sidx, tlbl, ew, partials);
    detr_finalize<<<1, 256, 0, stream>>>(partials, (float*)d_out);
}